// Round 1
// baseline (108.939 us; speedup 1.0000x reference)
//
#include <hip/hip_runtime.h>

#define NCH 20
#define RESOLUTION 64
#define PTS (RESOLUTION * RESOLUTION)   // 4096 spatial points per (b,c) slab

// Kernel 1: per-(b,c)-slab masked weighted reduction.
// grid = B*20 blocks, 256 threads. Each block reduces one slab:
//   fnx = sum m*(fvx*fd*64 + x), fny = sum m*(fvy*fd*64 + y)
//   bnx = sum m*(bvx*bd*64 + x), bny = sum m*(bvy*bd*64 + y)
//   den = sum m
__global__ __launch_bounds__(256) void vote_reduce(
    const float4* __restrict__ fv, const float4* __restrict__ fd,
    const float4* __restrict__ bv, const float4* __restrict__ bd,
    const float4* __restrict__ mk, float* __restrict__ sums)
{
    const int slab = blockIdx.x;                 // b*20 + c
    const int tid  = threadIdx.x;

    const float4* fvp = fv + (size_t)slab * (PTS * 2 / 4);  // 2048 float4
    const float4* bvp = bv + (size_t)slab * (PTS * 2 / 4);
    const float4* fdp = fd + (size_t)slab * (PTS / 4);      // 1024 float4
    const float4* bdp = bd + (size_t)slab * (PTS / 4);
    const float4* mkp = mk + (size_t)slab * (PTS / 4);

    float fnx = 0.f, fny = 0.f, bnx = 0.f, bny = 0.f, den = 0.f;

    #pragma unroll
    for (int g = 0; g < 4; ++g) {
        const int i = g * 256 + tid;             // 0..1023; covers points 4i..4i+3
        const float4 m4  = mkp[i];
        const float4 fd4 = fdp[i];
        const float4 bd4 = bdp[i];
        const float4 fva = fvp[2 * i], fvb = fvp[2 * i + 1];
        const float4 bva = bvp[2 * i], bvb = bvp[2 * i + 1];

        const float mm [4] = { m4.x,  m4.y,  m4.z,  m4.w  };
        const float fdd[4] = { fd4.x, fd4.y, fd4.z, fd4.w };
        const float bdd[4] = { bd4.x, bd4.y, bd4.z, bd4.w };
        const float fvx[4] = { fva.x, fva.z, fvb.x, fvb.z };
        const float fvy[4] = { fva.y, fva.w, fvb.y, fvb.w };
        const float bvx[4] = { bva.x, bva.z, bvb.x, bvb.z };
        const float bvy[4] = { bva.y, bva.w, bvb.y, bvb.w };

        const int p0 = i * 4;
        #pragma unroll
        for (int q = 0; q < 4; ++q) {
            const int p  = p0 + q;
            const float x = (float)(p >> 6);     // locs[...,0] = x
            const float y = (float)(p & 63);     // locs[...,1] = y
            const float m = mm[q];
            fnx += m * (fvx[q] * fdd[q] * 64.f + x);
            fny += m * (fvy[q] * fdd[q] * 64.f + y);
            bnx += m * (bvx[q] * bdd[q] * 64.f + x);
            bny += m * (bvy[q] * bdd[q] * 64.f + y);
            den += m;
        }
    }

    // 64-lane wave butterfly reduce
    #pragma unroll
    for (int off = 32; off > 0; off >>= 1) {
        fnx += __shfl_down(fnx, off);
        fny += __shfl_down(fny, off);
        bnx += __shfl_down(bnx, off);
        bny += __shfl_down(bny, off);
        den += __shfl_down(den, off);
    }

    __shared__ float red[4][5];
    const int wave = tid >> 6;
    const int lane = tid & 63;
    if (lane == 0) {
        red[wave][0] = fnx; red[wave][1] = fny;
        red[wave][2] = bnx; red[wave][3] = bny;
        red[wave][4] = den;
    }
    __syncthreads();
    if (tid == 0) {
        float s0 = 0.f, s1 = 0.f, s2 = 0.f, s3 = 0.f, s4 = 0.f;
        #pragma unroll
        for (int w = 0; w < 4; ++w) {
            s0 += red[w][0]; s1 += red[w][1];
            s2 += red[w][2]; s3 += red[w][3];
            s4 += red[w][4];
        }
        float* o = sums + (size_t)slab * 5;
        o[0] = s0; o[1] = s1; o[2] = s2; o[3] = s3; o[4] = s4;
    }
}

// Kernel 2: per-batch finalize. One thread per batch element.
__global__ __launch_bounds__(256) void combine(
    const float* __restrict__ sums, float* __restrict__ out, int B)
{
    const int b = blockIdx.x * blockDim.x + threadIdx.x;
    if (b >= B) return;

    float fsx[NCH], fsy[NCH], bsx[NCH], bsy[NCH];
    #pragma unroll
    for (int c = 0; c < NCH; ++c) {
        const float* s = sums + (size_t)(b * NCH + c) * 5;
        const float inv = 1.f / (s[4] + 1e-6f);
        fsx[c] = s[0] * inv; fsy[c] = s[1] * inv;
        bsx[c] = s[2] * inv; bsy[c] = s[3] * inv;
    }

    // wrist = mean of back predictions at channels 0,4,8,12,16
    const float k0x = 0.2f * (bsx[0] + bsx[4] + bsx[8] + bsx[12] + bsx[16]);
    const float k0y = 0.2f * (bsy[0] + bsy[4] + bsy[8] + bsy[12] + bsy[16]);

    float* o = out + (size_t)b * 42;             // 21 keypoints * 2
    o[0] = k0x * 4.f;
    o[1] = k0y * 4.f;

    #pragma unroll
    for (int c = 0; c < NCH; ++c) {
        const int j = c & 3;
        const int t = (c & ~3) + 4 - j;          // target keypoint 1..20
        float vx, vy;
        if (j == 3) {
            vx = fsx[c]; vy = fsy[c];
        } else {
            vx = 0.5f * (fsx[c] + bsx[c + 1]);
            vy = 0.5f * (fsy[c] + bsy[c + 1]);
        }
        o[t * 2]     = vx * 4.f;
        o[t * 2 + 1] = vy * 4.f;
    }
}

extern "C" void kernel_launch(void* const* d_in, const int* in_sizes, int n_in,
                              void* d_out, int out_size, void* d_ws, size_t ws_size,
                              hipStream_t stream) {
    const float4* fv = (const float4*)d_in[0];   // [B,20,64,64,2]
    const float4* fd = (const float4*)d_in[1];   // [B,20,64,64,1]
    const float4* bv = (const float4*)d_in[2];
    const float4* bd = (const float4*)d_in[3];
    const float4* mk = (const float4*)d_in[4];

    const int B = in_sizes[0] / (NCH * PTS * 2); // 256
    float* sums = (float*)d_ws;                  // [B*20][5] floats
    float* out  = (float*)d_out;

    vote_reduce<<<B * NCH, 256, 0, stream>>>(fv, fd, bv, bd, mk, sums);
    combine<<<(B + 255) / 256, 256, 0, stream>>>(sums, out, B);
}

// Round 2
// 103.418 us; speedup vs baseline: 1.0534x; 1.0534x over previous
//
#include <hip/hip_runtime.h>

#define NCH 20
#define RESOLUTION 64
#define PTS (RESOLUTION * RESOLUTION)   // 4096 spatial points per (b,c) slab

// Kernel 1: per-(b,c)-slab masked weighted reduction.
// grid = B*20 blocks, 256 threads. All 28 float4 loads per thread are issued
// up-front into register arrays (static indexing after full unroll) so each
// wave keeps 28 global loads outstanding -> latency-bound -> BW-bound.
__global__ __launch_bounds__(256) void vote_reduce(
    const float4* __restrict__ fv, const float4* __restrict__ fd,
    const float4* __restrict__ bv, const float4* __restrict__ bd,
    const float4* __restrict__ mk, float* __restrict__ sums)
{
    const int slab = blockIdx.x;                 // b*20 + c
    const int tid  = threadIdx.x;

    const float4* fvp = fv + (size_t)slab * (PTS * 2 / 4);  // 2048 float4
    const float4* bvp = bv + (size_t)slab * (PTS * 2 / 4);
    const float4* fdp = fd + (size_t)slab * (PTS / 4);      // 1024 float4
    const float4* bdp = bd + (size_t)slab * (PTS / 4);
    const float4* mkp = mk + (size_t)slab * (PTS / 4);

    // ---- issue ALL loads first: 28 float4 in flight per thread ----
    float4 m4[4], fd4[4], bd4[4], fva[4], fvb[4], bva[4], bvb[4];
    #pragma unroll
    for (int g = 0; g < 4; ++g) {
        const int i = g * 256 + tid;             // 0..1023; covers points 4i..4i+3
        fva[g] = fvp[2 * i];
        fvb[g] = fvp[2 * i + 1];
        bva[g] = bvp[2 * i];
        bvb[g] = bvp[2 * i + 1];
        fd4[g] = fdp[i];
        bd4[g] = bdp[i];
        m4[g]  = mkp[i];
    }

    // ---- consume ----
    float fnx = 0.f, fny = 0.f, bnx = 0.f, bny = 0.f, den = 0.f;
    #pragma unroll
    for (int g = 0; g < 4; ++g) {
        const int i = g * 256 + tid;
        const float mm [4] = { m4[g].x,  m4[g].y,  m4[g].z,  m4[g].w  };
        const float fdd[4] = { fd4[g].x, fd4[g].y, fd4[g].z, fd4[g].w };
        const float bdd[4] = { bd4[g].x, bd4[g].y, bd4[g].z, bd4[g].w };
        const float fvx[4] = { fva[g].x, fva[g].z, fvb[g].x, fvb[g].z };
        const float fvy[4] = { fva[g].y, fva[g].w, fvb[g].y, fvb[g].w };
        const float bvx[4] = { bva[g].x, bva[g].z, bvb[g].x, bvb[g].z };
        const float bvy[4] = { bva[g].y, bva[g].w, bvb[g].y, bvb[g].w };

        const int p0 = i * 4;
        #pragma unroll
        for (int q = 0; q < 4; ++q) {
            const int p  = p0 + q;
            const float x = (float)(p >> 6);     // locs[...,0] = x
            const float y = (float)(p & 63);     // locs[...,1] = y
            const float m = mm[q];
            fnx += m * (fvx[q] * fdd[q] * 64.f + x);
            fny += m * (fvy[q] * fdd[q] * 64.f + y);
            bnx += m * (bvx[q] * bdd[q] * 64.f + x);
            bny += m * (bvy[q] * bdd[q] * 64.f + y);
            den += m;
        }
    }

    // ---- 64-lane wave butterfly reduce ----
    #pragma unroll
    for (int off = 32; off > 0; off >>= 1) {
        fnx += __shfl_down(fnx, off);
        fny += __shfl_down(fny, off);
        bnx += __shfl_down(bnx, off);
        bny += __shfl_down(bny, off);
        den += __shfl_down(den, off);
    }

    __shared__ float red[4][5];
    const int wave = tid >> 6;
    const int lane = tid & 63;
    if (lane == 0) {
        red[wave][0] = fnx; red[wave][1] = fny;
        red[wave][2] = bnx; red[wave][3] = bny;
        red[wave][4] = den;
    }
    __syncthreads();
    if (tid == 0) {
        float s0 = 0.f, s1 = 0.f, s2 = 0.f, s3 = 0.f, s4 = 0.f;
        #pragma unroll
        for (int w = 0; w < 4; ++w) {
            s0 += red[w][0]; s1 += red[w][1];
            s2 += red[w][2]; s3 += red[w][3];
            s4 += red[w][4];
        }
        float* o = sums + (size_t)slab * 5;
        o[0] = s0; o[1] = s1; o[2] = s2; o[3] = s3; o[4] = s4;
    }
}

// Kernel 2: per-batch finalize. One thread per batch element, spread over
// 4 blocks of 64 so it doesn't serialize on a single CU.
__global__ __launch_bounds__(64) void combine(
    const float* __restrict__ sums, float* __restrict__ out, int B)
{
    const int b = blockIdx.x * blockDim.x + threadIdx.x;
    if (b >= B) return;

    float fsx[NCH], fsy[NCH], bsx[NCH], bsy[NCH];
    #pragma unroll
    for (int c = 0; c < NCH; ++c) {
        const float* s = sums + (size_t)(b * NCH + c) * 5;
        const float inv = 1.f / (s[4] + 1e-6f);
        fsx[c] = s[0] * inv; fsy[c] = s[1] * inv;
        bsx[c] = s[2] * inv; bsy[c] = s[3] * inv;
    }

    // wrist = mean of back predictions at channels 0,4,8,12,16
    const float k0x = 0.2f * (bsx[0] + bsx[4] + bsx[8] + bsx[12] + bsx[16]);
    const float k0y = 0.2f * (bsy[0] + bsy[4] + bsy[8] + bsy[12] + bsy[16]);

    float* o = out + (size_t)b * 42;             // 21 keypoints * 2
    o[0] = k0x * 4.f;
    o[1] = k0y * 4.f;

    #pragma unroll
    for (int c = 0; c < NCH; ++c) {
        const int j = c & 3;
        const int t = (c & ~3) + 4 - j;          // target keypoint 1..20
        float vx, vy;
        if (j == 3) {
            vx = fsx[c]; vy = fsy[c];
        } else {
            vx = 0.5f * (fsx[c] + bsx[c + 1]);
            vy = 0.5f * (fsy[c] + bsy[c + 1]);
        }
        o[t * 2]     = vx * 4.f;
        o[t * 2 + 1] = vy * 4.f;
    }
}

extern "C" void kernel_launch(void* const* d_in, const int* in_sizes, int n_in,
                              void* d_out, int out_size, void* d_ws, size_t ws_size,
                              hipStream_t stream) {
    const float4* fv = (const float4*)d_in[0];   // [B,20,64,64,2]
    const float4* fd = (const float4*)d_in[1];   // [B,20,64,64,1]
    const float4* bv = (const float4*)d_in[2];
    const float4* bd = (const float4*)d_in[3];
    const float4* mk = (const float4*)d_in[4];

    const int B = in_sizes[0] / (NCH * PTS * 2); // 256
    float* sums = (float*)d_ws;                  // [B*20][5] floats
    float* out  = (float*)d_out;

    vote_reduce<<<B * NCH, 256, 0, stream>>>(fv, fd, bv, bd, mk, sums);
    combine<<<(B + 63) / 64, 64, 0, stream>>>(sums, out, B);
}